// Round 3
// baseline (72.102 us; speedup 1.0000x reference)
//
#include <hip/hip_runtime.h>

#define N_NODES   10000
#define M_PAD     10112          // 79 * 128
#define DEG       32
#define IN_FEATS  256
#define HEADS     8
#define OUT_FEATS 64
#define HD        512
#define NEG_SLOPE 0.2f

typedef short bf16x8 __attribute__((ext_vector_type(8)));
typedef float f32x4  __attribute__((ext_vector_type(4)));

__device__ __forceinline__ ushort f2bf(float x) {
    union { float f; unsigned u; } c; c.f = x;
    unsigned r = (c.u + 0x7fffu + ((c.u >> 16) & 1u)) >> 16;   // RNE
    return (ushort)r;
}
__device__ __forceinline__ float bfbits2f(unsigned hi_bits) {  // bits already in [31:16]
    union { unsigned u; float f; } c; c.u = hi_bits;
    return c.f;
}

// ---------------------------------------------------------------------------
// feat fp32 -> bf16
// ---------------------------------------------------------------------------
__global__ __launch_bounds__(256) void convert_feat(const float* __restrict__ f,
                                                    ushort* __restrict__ fb) {
    const int i = blockIdx.x * 256 + threadIdx.x;   // float4 index
    const float4 v = reinterpret_cast<const float4*>(f)[i];
    ushort4 o;
    o.x = f2bf(v.x); o.y = f2bf(v.y); o.z = f2bf(v.z); o.w = f2bf(v.w);
    reinterpret_cast<ushort4*>(fb)[i] = o;
}

// ---------------------------------------------------------------------------
// W [K=256][N=512] fp32 -> W_bt [N=512][K=256] bf16 (transpose via LDS tile)
// ---------------------------------------------------------------------------
__global__ __launch_bounds__(256) void convert_W(const float* __restrict__ W,
                                                 ushort* __restrict__ Bt) {
    __shared__ ushort s[64][72];
    const int kb = blockIdx.x * 64;
    const int nb = blockIdx.y * 64;
    const int t  = threadIdx.x;
    #pragma unroll
    for (int rep = 0; rep < 4; ++rep) {
        const int kk = rep * 16 + (t >> 4);
        const int nn = (t & 15) * 4;
        const float4 v = *reinterpret_cast<const float4*>(&W[(size_t)(kb + kk) * HD + nb + nn]);
        s[nn + 0][kk] = f2bf(v.x);
        s[nn + 1][kk] = f2bf(v.y);
        s[nn + 2][kk] = f2bf(v.z);
        s[nn + 3][kk] = f2bf(v.w);
    }
    __syncthreads();
    const int nn = t >> 2;
    const int k0 = (t & 3) * 16;
    #pragma unroll
    for (int c = 0; c < 2; ++c) {
        *reinterpret_cast<uint4*>(&Bt[(size_t)(nb + nn) * IN_FEATS + kb + k0 + c * 8]) =
            *reinterpret_cast<const uint4*>(&s[nn][k0 + c * 8]);
    }
}

// ---------------------------------------------------------------------------
// ft_bf16 = feat_bf @ W_bt^T : 128x128 tile, BK=32, mfma_f32_16x16x32_bf16.
// ---------------------------------------------------------------------------
__global__ __launch_bounds__(256) void gemm_mfma(const ushort* __restrict__ A,
                                                 const ushort* __restrict__ Bt,
                                                 ushort* __restrict__ C) {
    __shared__ ushort As[128 * 32];
    __shared__ ushort Bs[128 * 32];
    const int t    = threadIdx.x;
    const int lane = t & 63;
    const int m0   = blockIdx.x * 128;
    const int n0   = blockIdx.y * 128;
    const int wave = t >> 6;
    const int wr   = (wave >> 1) * 64;
    const int wc   = (wave & 1) * 64;

    const int srow0 = t >> 2;
    const int srow1 = 64 + (t >> 2);
    const int sq    = t & 3;
    const int sq0   = sq ^ ((srow0 >> 1) & 3);
    const int sq1   = sq ^ ((srow1 >> 1) & 3);

    uint4 ra0, ra1, rb0, rb1;
#define LOADREGS(K0)                                                                   \
    do {                                                                               \
        ra0 = *reinterpret_cast<const uint4*>(A  + (size_t)(m0 + srow0) * IN_FEATS + (K0) + sq * 8); \
        ra1 = *reinterpret_cast<const uint4*>(A  + (size_t)(m0 + srow1) * IN_FEATS + (K0) + sq * 8); \
        rb0 = *reinterpret_cast<const uint4*>(Bt + (size_t)(n0 + srow0) * IN_FEATS + (K0) + sq * 8); \
        rb1 = *reinterpret_cast<const uint4*>(Bt + (size_t)(n0 + srow1) * IN_FEATS + (K0) + sq * 8); \
    } while (0)

    f32x4 acc[4][4];
    #pragma unroll
    for (int i = 0; i < 4; ++i)
        #pragma unroll
        for (int j = 0; j < 4; ++j)
            acc[i][j] = (f32x4){0.f, 0.f, 0.f, 0.f};

    const int rqoff = (((lane >> 4) ^ (((lane & 15) >> 1) & 3)) * 8);
    const int rl    = lane & 15;

    LOADREGS(0);
    for (int k0 = 0; k0 < IN_FEATS; k0 += 32) {
        __syncthreads();
        *reinterpret_cast<uint4*>(As + srow0 * 32 + sq0 * 8) = ra0;
        *reinterpret_cast<uint4*>(As + srow1 * 32 + sq1 * 8) = ra1;
        *reinterpret_cast<uint4*>(Bs + srow0 * 32 + sq0 * 8) = rb0;
        *reinterpret_cast<uint4*>(Bs + srow1 * 32 + sq1 * 8) = rb1;
        __syncthreads();
        if (k0 + 32 < IN_FEATS) LOADREGS(k0 + 32);

        bf16x8 af[4], bfr[4];
        #pragma unroll
        for (int i = 0; i < 4; ++i)
            af[i] = *reinterpret_cast<const bf16x8*>(As + (wr + i * 16 + rl) * 32 + rqoff);
        #pragma unroll
        for (int j = 0; j < 4; ++j)
            bfr[j] = *reinterpret_cast<const bf16x8*>(Bs + (wc + j * 16 + rl) * 32 + rqoff);
        #pragma unroll
        for (int i = 0; i < 4; ++i)
            #pragma unroll
            for (int j = 0; j < 4; ++j)
                acc[i][j] = __builtin_amdgcn_mfma_f32_16x16x32_bf16(af[i], bfr[j], acc[i][j], 0, 0, 0);
    }
#undef LOADREGS

    const int rbase = (lane >> 4) * 4;
    #pragma unroll
    for (int i = 0; i < 4; ++i) {
        #pragma unroll
        for (int r = 0; r < 4; ++r) {
            const int gm = m0 + wr + i * 16 + rbase + r;
            ushort* dst = C + (size_t)gm * HD + n0 + wc + rl;
            #pragma unroll
            for (int j = 0; j < 4; ++j)
                dst[j * 16] = f2bf(acc[i][j][r]);
        }
    }
}

// ---------------------------------------------------------------------------
// el[n,h] = dot(ft[n,h,:], attn_l[h,:]);  er likewise. One wave per (n,h).
// ---------------------------------------------------------------------------
__global__ __launch_bounds__(256) void logits_kernel(const ushort* __restrict__ ftb,
                                                     const float* __restrict__ attn_l,
                                                     const float* __restrict__ attn_r,
                                                     float* __restrict__ el,
                                                     float* __restrict__ er) {
    const int wave = threadIdx.x >> 6;
    const int lane = threadIdx.x & 63;
    const int idx  = blockIdx.x * 4 + wave;   // n*HEADS + h
    if (idx >= N_NODES * HEADS) return;
    const int n = idx >> 3;
    const int h = idx & 7;

    const float v = bfbits2f((unsigned)ftb[(size_t)n * HD + h * OUT_FEATS + lane] << 16);
    float vl = v * attn_l[h * OUT_FEATS + lane];
    float vr = v * attn_r[h * OUT_FEATS + lane];
    #pragma unroll
    for (int m = 32; m; m >>= 1) {
        vl += __shfl_xor(vl, m, 64);
        vr += __shfl_xor(vr, m, 64);
    }
    if (lane == 0) {
        el[idx] = vl;
        er[idx] = vr;
    }
}

// ---------------------------------------------------------------------------
// Per-node edge softmax -> out_a [N][DEG][HEADS]. One block per node.
// ---------------------------------------------------------------------------
__global__ __launch_bounds__(256) void softmax_kernel(const float* __restrict__ el,
                                                      const float* __restrict__ er,
                                                      const int* __restrict__ src,
                                                      float* __restrict__ out_a) {
    __shared__ int   s_src[DEG];
    __shared__ float s_a[DEG][HEADS];

    const int n = blockIdx.x;
    const int t = threadIdx.x;

    if (t < DEG) s_src[t] = src[n * DEG + t];
    __syncthreads();

    const int h = t >> 5;
    const int j = t & 31;
    const int s = s_src[j];
    float e = el[s * HEADS + h] + er[n * HEADS + h];
    e = (e > 0.f) ? e : NEG_SLOPE * e;

    float m = e;
    #pragma unroll
    for (int msk = 16; msk; msk >>= 1) m = fmaxf(m, __shfl_xor(m, msk, 64));
    const float ex = __expf(e - m);
    float sum = ex;
    #pragma unroll
    for (int msk = 16; msk; msk >>= 1) sum += __shfl_xor(sum, msk, 64);
    s_a[j][h] = ex / sum;
    __syncthreads();

    out_a[(size_t)n * 256 + t] = s_a[t >> 3][t & 7];
}

// ---------------------------------------------------------------------------
// Aggregation, column-blocked for L2 residency.
// grid = (N_NODES/4, 4): blockIdx.y = col-block of 128 cols (2 heads);
// the gathered slice ft[:, cb*128 : cb*128+128] is 2.56 MB -> fits per-XCD L2.
// One wave per node; lane owns one dword (2 bf16 cols).
// ---------------------------------------------------------------------------
__global__ __launch_bounds__(256) void agg_col(const uint* __restrict__ ftb_dw,
                                               const float* __restrict__ out_a,
                                               const int* __restrict__ src,
                                               float* __restrict__ rst) {
    __shared__ int   s_src[4][DEG];
    __shared__ float s_a[4][DEG][2];

    const int w  = threadIdx.x >> 6;
    const int l  = threadIdx.x & 63;
    const int n  = blockIdx.x * 4 + w;
    const int cb = blockIdx.y;

    if (l < DEG) {
        s_src[w][l] = src[n * DEG + l];
        const float2 av = *reinterpret_cast<const float2*>(&out_a[(size_t)n * 256 + l * 8 + cb * 2]);
        s_a[w][l][0] = av.x;
        s_a[w][l][1] = av.y;
    }
    __syncthreads();

    const int hsel  = l >> 5;             // which of the 2 heads in this col-block
    const int dwcol = cb * 64 + l;        // dword col within the 256-dword row
    float a0 = 0.f, a1 = 0.f;
    #pragma unroll 8
    for (int jj = 0; jj < DEG; ++jj) {
        const uint  u  = ftb_dw[(size_t)s_src[w][jj] * 256 + dwcol];
        const float wt = s_a[w][jj][hsel];
        a0 = fmaf(wt, bfbits2f(u << 16), a0);
        a1 = fmaf(wt, bfbits2f(u & 0xffff0000u), a1);
    }
    *reinterpret_cast<float2*>(&rst[(size_t)n * HD + cb * 128 + 2 * l]) = make_float2(a0, a1);
}

// ---------------------------------------------------------------------------
extern "C" void kernel_launch(void* const* d_in, const int* in_sizes, int n_in,
                              void* d_out, int out_size, void* d_ws, size_t ws_size,
                              hipStream_t stream) {
    const float* feat   = (const float*)d_in[0];
    const float* W      = (const float*)d_in[1];
    const float* attn_l = (const float*)d_in[2];
    const float* attn_r = (const float*)d_in[3];
    const int*   src    = (const int*)d_in[4];

    float* out_rst = (float*)d_out;                     // [N, H, D]
    float* out_a   = out_rst + (size_t)N_NODES * HD;    // [E, H, 1]

    char* w = (char*)d_ws;
    ushort* feat_bf = (ushort*)w;  w += (size_t)M_PAD * IN_FEATS * 2;
    ushort* W_bt    = (ushort*)w;  w += (size_t)HD * IN_FEATS * 2;
    ushort* ftb     = (ushort*)w;  w += (size_t)M_PAD * HD * 2;
    float*  el      = (float*)w;   w += (size_t)N_NODES * HEADS * 4;
    float*  er      = (float*)w;

    convert_feat<<<(N_NODES * IN_FEATS / 4) / 256, 256, 0, stream>>>(feat, feat_bf);
    convert_W<<<dim3(IN_FEATS / 64, HD / 64), 256, 0, stream>>>(W, W_bt);
    gemm_mfma<<<dim3(M_PAD / 128, HD / 128), 256, 0, stream>>>(feat_bf, W_bt, ftb);
    logits_kernel<<<(N_NODES * HEADS + 3) / 4, 256, 0, stream>>>(ftb, attn_l, attn_r, el, er);
    softmax_kernel<<<N_NODES, 256, 0, stream>>>(el, er, src, out_a);
    agg_col<<<dim3(N_NODES / 4, 4), 256, 0, stream>>>((const uint*)ftb, out_a, src, out_rst);
}

// Round 4
// 56.167 us; speedup vs baseline: 1.2837x; 1.2837x over previous
//
#include <hip/hip_runtime.h>

#define N_NODES   10000
#define M_PAD     10112          // 79 * 128
#define DEG       32
#define IN_FEATS  256
#define HEADS     8
#define OUT_FEATS 64
#define HD        512
#define NEG_SLOPE 0.2f

typedef short bf16x8 __attribute__((ext_vector_type(8)));
typedef float f32x4  __attribute__((ext_vector_type(4)));

__device__ __forceinline__ ushort f2bf(float x) {
    union { float f; unsigned u; } c; c.f = x;
    unsigned r = (c.u + 0x7fffu + ((c.u >> 16) & 1u)) >> 16;   // RNE
    return (ushort)r;
}
__device__ __forceinline__ float bfbits2f(unsigned hi_bits) {  // bits already in [31:16]
    union { unsigned u; float f; } c; c.u = hi_bits;
    return c.f;
}

// ---------------------------------------------------------------------------
// Fused converts: blocks [0,2500) feat fp32->bf16; blocks [2500,2532) W
// transpose+convert to W_bt [N=512][K=256] bf16.
// ---------------------------------------------------------------------------
__global__ __launch_bounds__(256) void convert_all(const float* __restrict__ f,
                                                   ushort* __restrict__ fb,
                                                   const float* __restrict__ W,
                                                   ushort* __restrict__ Bt) {
    __shared__ ushort s[64][72];
    const int b = blockIdx.x;
    const int t = threadIdx.x;
    if (b < 2500) {
        const int i = b * 256 + t;   // float4 index
        const float4 v = reinterpret_cast<const float4*>(f)[i];
        ushort4 o;
        o.x = f2bf(v.x); o.y = f2bf(v.y); o.z = f2bf(v.z); o.w = f2bf(v.w);
        reinterpret_cast<ushort4*>(fb)[i] = o;
        return;
    }
    const int bb = b - 2500;             // 0..31
    const int kb = (bb & 3) * 64;
    const int nb = (bb >> 2) * 64;
    #pragma unroll
    for (int rep = 0; rep < 4; ++rep) {
        const int kk = rep * 16 + (t >> 4);
        const int nn = (t & 15) * 4;
        const float4 v = *reinterpret_cast<const float4*>(&W[(size_t)(kb + kk) * HD + nb + nn]);
        s[nn + 0][kk] = f2bf(v.x);
        s[nn + 1][kk] = f2bf(v.y);
        s[nn + 2][kk] = f2bf(v.z);
        s[nn + 3][kk] = f2bf(v.w);
    }
    __syncthreads();
    const int nn = t >> 2;
    const int k0 = (t & 3) * 16;
    #pragma unroll
    for (int c = 0; c < 2; ++c) {
        *reinterpret_cast<uint4*>(&Bt[(size_t)(nb + nn) * IN_FEATS + kb + k0 + c * 8]) =
            *reinterpret_cast<const uint4*>(&s[nn][k0 + c * 8]);
    }
}

// ---------------------------------------------------------------------------
// ft = feat_bf @ W_bt^T (128x128 tile, BK=32, mfma 16x16x32 bf16) with fused
// el/er epilogue: each wave's 64-col span is exactly one head ->
// el[n,h] = sum_d ft[n,h,d]*attn_l[h,d] computed from the fp32 accumulator
// (4 muls + 4 shfl_xor per output row).
// ---------------------------------------------------------------------------
__global__ __launch_bounds__(256) void gemm_logits(const ushort* __restrict__ A,
                                                   const ushort* __restrict__ Bt,
                                                   const float* __restrict__ attn_l,
                                                   const float* __restrict__ attn_r,
                                                   ushort* __restrict__ C,
                                                   float* __restrict__ el,
                                                   float* __restrict__ er) {
    __shared__ ushort As[128 * 32];
    __shared__ ushort Bs[128 * 32];
    const int t    = threadIdx.x;
    const int lane = t & 63;
    const int m0   = blockIdx.x * 128;
    const int n0   = blockIdx.y * 128;
    const int wave = t >> 6;
    const int wr   = (wave >> 1) * 64;
    const int wc   = (wave & 1) * 64;

    const int srow0 = t >> 2;
    const int srow1 = 64 + (t >> 2);
    const int sq    = t & 3;
    const int sq0   = sq ^ ((srow0 >> 1) & 3);
    const int sq1   = sq ^ ((srow1 >> 1) & 3);

    uint4 ra0, ra1, rb0, rb1;
#define LOADREGS(K0)                                                                   \
    do {                                                                               \
        ra0 = *reinterpret_cast<const uint4*>(A  + (size_t)(m0 + srow0) * IN_FEATS + (K0) + sq * 8); \
        ra1 = *reinterpret_cast<const uint4*>(A  + (size_t)(m0 + srow1) * IN_FEATS + (K0) + sq * 8); \
        rb0 = *reinterpret_cast<const uint4*>(Bt + (size_t)(n0 + srow0) * IN_FEATS + (K0) + sq * 8); \
        rb1 = *reinterpret_cast<const uint4*>(Bt + (size_t)(n0 + srow1) * IN_FEATS + (K0) + sq * 8); \
    } while (0)

    f32x4 acc[4][4];
    #pragma unroll
    for (int i = 0; i < 4; ++i)
        #pragma unroll
        for (int j = 0; j < 4; ++j)
            acc[i][j] = (f32x4){0.f, 0.f, 0.f, 0.f};

    const int rqoff = (((lane >> 4) ^ (((lane & 15) >> 1) & 3)) * 8);
    const int rl    = lane & 15;

    LOADREGS(0);
    for (int k0 = 0; k0 < IN_FEATS; k0 += 32) {
        __syncthreads();
        *reinterpret_cast<uint4*>(As + srow0 * 32 + sq0 * 8) = ra0;
        *reinterpret_cast<uint4*>(As + srow1 * 32 + sq1 * 8) = ra1;
        *reinterpret_cast<uint4*>(Bs + srow0 * 32 + sq0 * 8) = rb0;
        *reinterpret_cast<uint4*>(Bs + srow1 * 32 + sq1 * 8) = rb1;
        __syncthreads();
        if (k0 + 32 < IN_FEATS) LOADREGS(k0 + 32);

        bf16x8 af[4], bfr[4];
        #pragma unroll
        for (int i = 0; i < 4; ++i)
            af[i] = *reinterpret_cast<const bf16x8*>(As + (wr + i * 16 + rl) * 32 + rqoff);
        #pragma unroll
        for (int j = 0; j < 4; ++j)
            bfr[j] = *reinterpret_cast<const bf16x8*>(Bs + (wc + j * 16 + rl) * 32 + rqoff);
        #pragma unroll
        for (int i = 0; i < 4; ++i)
            #pragma unroll
            for (int j = 0; j < 4; ++j)
                acc[i][j] = __builtin_amdgcn_mfma_f32_16x16x32_bf16(af[i], bfr[j], acc[i][j], 0, 0, 0);
    }
#undef LOADREGS

    // ---- epilogue: C store + fused el/er ----
    const int g    = lane >> 4;          // row group 0..3
    const int hblk = (n0 + wc) >> 6;     // this wave's head (0..7)
    float al[4], ar[4];
    #pragma unroll
    for (int j = 0; j < 4; ++j) {
        al[j] = attn_l[hblk * OUT_FEATS + j * 16 + rl];
        ar[j] = attn_r[hblk * OUT_FEATS + j * 16 + rl];
    }

    #pragma unroll
    for (int i = 0; i < 4; ++i) {
        #pragma unroll
        for (int r = 0; r < 4; ++r) {
            const int gm = m0 + wr + i * 16 + g * 4 + r;
            ushort* dst = C + (size_t)gm * HD + n0 + wc + rl;
            float sl = 0.f, sr = 0.f;
            #pragma unroll
            for (int j = 0; j < 4; ++j) {
                dst[j * 16] = f2bf(acc[i][j][r]);
                sl = fmaf(acc[i][j][r], al[j], sl);
                sr = fmaf(acc[i][j][r], ar[j], sr);
            }
            sl += __shfl_xor(sl, 1, 64); sr += __shfl_xor(sr, 1, 64);
            sl += __shfl_xor(sl, 2, 64); sr += __shfl_xor(sr, 2, 64);
            sl += __shfl_xor(sl, 4, 64); sr += __shfl_xor(sr, 4, 64);
            sl += __shfl_xor(sl, 8, 64); sr += __shfl_xor(sr, 8, 64);
            if (rl == 0 && gm < N_NODES) {
                el[gm * HEADS + hblk] = sl;
                er[gm * HEADS + hblk] = sr;
            }
        }
    }
}

// ---------------------------------------------------------------------------
// Per-node edge softmax. Writes out_a (required [E,H,1] layout) AND a
// head-contiguous copy a_t[n][h][j] so agg slices read only their head.
// ---------------------------------------------------------------------------
__global__ __launch_bounds__(256) void softmax_kernel(const float* __restrict__ el,
                                                      const float* __restrict__ er,
                                                      const int* __restrict__ src,
                                                      float* __restrict__ out_a,
                                                      float* __restrict__ a_t) {
    __shared__ int   s_src[DEG];
    __shared__ float s_a[DEG][HEADS];

    const int n = blockIdx.x;
    const int t = threadIdx.x;

    if (t < DEG) s_src[t] = src[n * DEG + t];
    __syncthreads();

    const int h = t >> 5;
    const int j = t & 31;
    const int s = s_src[j];
    float e = el[s * HEADS + h] + er[n * HEADS + h];
    e = (e > 0.f) ? e : NEG_SLOPE * e;

    float m = e;
    #pragma unroll
    for (int msk = 16; msk; msk >>= 1) m = fmaxf(m, __shfl_xor(m, msk, 64));
    const float ex = __expf(e - m);
    float sum = ex;
    #pragma unroll
    for (int msk = 16; msk; msk >>= 1) sum += __shfl_xor(sum, msk, 64);
    s_a[j][h] = ex / sum;
    __syncthreads();

    out_a[(size_t)n * 256 + t] = s_a[t >> 3][t & 7];     // [j][h] layout
    a_t[(size_t)n * 256 + t]   = s_a[t & 31][t >> 5];    // [h][j] layout
}

// ---------------------------------------------------------------------------
// XCD-partitioned aggregation. slice = blockIdx&7 (== XCD via round-robin
// dispatch): each XCD gathers ONLY from its 64-col (1-head) slice of ft
// (1.28 MB -> L2-resident). Block: 4 waves, 2 nodes/wave (32 lanes/node,
// lane owns 1 dword = 2 bf16 cols).
// ---------------------------------------------------------------------------
__global__ __launch_bounds__(256) void agg_xcd(const uint* __restrict__ ftb_dw,
                                               const float* __restrict__ a_t,
                                               const int* __restrict__ src,
                                               float* __restrict__ rst) {
    __shared__ int   s_src[8][DEG];
    __shared__ float s_a[8][DEG];

    const int b     = blockIdx.x;
    const int slice = b & 7;             // head / XCD slice
    const int chunk = b >> 3;            // node chunk (8 nodes)
    const int w     = threadIdx.x >> 6;
    const int l     = threadIdx.x & 63;
    const int hi    = l >> 5;            // which node of the wave's pair
    const int li    = l & 31;
    const int wn    = 2 * w + hi;        // local node 0..7
    const int n     = chunk * 8 + wn;

    // wave-local staging (each wave reads only what it wrote -> no barrier)
    s_src[wn][li] = src[n * DEG + li];
    s_a[wn][li]   = a_t[(size_t)n * 256 + slice * 32 + li];

    const int dwcol = slice * 32 + li;   // dword col in the 256-dword row
    float a0 = 0.f, a1 = 0.f;
    #pragma unroll 8
    for (int j = 0; j < DEG; ++j) {
        const uint  u  = ftb_dw[(size_t)s_src[wn][j] * 256 + dwcol];
        const float wt = s_a[wn][j];
        a0 = fmaf(wt, bfbits2f(u << 16), a0);
        a1 = fmaf(wt, bfbits2f(u & 0xffff0000u), a1);
    }
    *reinterpret_cast<float2*>(&rst[(size_t)n * HD + slice * 64 + 2 * li]) = make_float2(a0, a1);
}

// ---------------------------------------------------------------------------
extern "C" void kernel_launch(void* const* d_in, const int* in_sizes, int n_in,
                              void* d_out, int out_size, void* d_ws, size_t ws_size,
                              hipStream_t stream) {
    const float* feat   = (const float*)d_in[0];
    const float* W      = (const float*)d_in[1];
    const float* attn_l = (const float*)d_in[2];
    const float* attn_r = (const float*)d_in[3];
    const int*   src    = (const int*)d_in[4];

    float* out_rst = (float*)d_out;                     // [N, H, D]
    float* out_a   = out_rst + (size_t)N_NODES * HD;    // [E, H, 1]

    char* w = (char*)d_ws;
    ushort* feat_bf = (ushort*)w;  w += (size_t)M_PAD * IN_FEATS * 2;
    ushort* W_bt    = (ushort*)w;  w += (size_t)HD * IN_FEATS * 2;
    ushort* ftb     = (ushort*)w;  w += (size_t)M_PAD * HD * 2;
    float*  el      = (float*)w;   w += (size_t)N_NODES * HEADS * 4;
    float*  er      = (float*)w;   w += (size_t)N_NODES * HEADS * 4;
    float*  a_t     = (float*)w;   w += (size_t)N_NODES * 256 * 4;

    convert_all<<<2532, 256, 0, stream>>>(feat, feat_bf, W, W_bt);
    gemm_logits<<<dim3(M_PAD / 128, HD / 128), 256, 0, stream>>>(feat_bf, W_bt, attn_l, attn_r,
                                                                 ftb, el, er);
    softmax_kernel<<<N_NODES, 256, 0, stream>>>(el, er, src, out_a, a_t);
    agg_xcd<<<N_NODES / 8 * 8, 256, 0, stream>>>((const uint*)ftb, a_t, src, out_rst);
}